// Round 1
// baseline (30091.360 us; speedup 1.0000x reference)
//
#include <hip/hip_runtime.h>
#include <hip/hip_bf16.h>

typedef unsigned short u16;
typedef short s8v __attribute__((ext_vector_type(8)));
typedef float f4v __attribute__((ext_vector_type(4)));

#define BQ 32
#define TQ 512
#define DQ 1024
#define NBLK 256
#define NTHR 256

__device__ __host__ inline u16 f2bf(float f) {
    union { float f; unsigned u; } v; v.f = f;
    unsigned r = v.u + 0x7fffu + ((v.u >> 16) & 1u);  // RNE
    return (u16)(r >> 16);
}
__device__ __host__ inline float bf2f(u16 u) {
    union { unsigned u; float f; } v; v.u = ((unsigned)u) << 16;
    return v.f;
}

// Pre-split x into bf16 hi/lo planes; zero h buffers and barrier counters.
__global__ void init_kernel(const float* __restrict__ x,
                            u16* __restrict__ x_hi, u16* __restrict__ x_lo,
                            u16* __restrict__ h0, u16* __restrict__ h1,
                            unsigned* __restrict__ cnt) {
    size_t i = (size_t)blockIdx.x * blockDim.x + threadIdx.x;
    size_t stride = (size_t)gridDim.x * blockDim.x;
    const size_t N = (size_t)BQ * TQ * DQ;
    for (size_t idx = i; idx < N; idx += stride) {
        float v = x[idx];
        u16 hh = f2bf(v);
        x_hi[idx] = hh;
        x_lo[idx] = f2bf(v - bf2f(hh));
    }
    const size_t HN = 4 * (size_t)BQ * DQ;  // 2 bufs * 2 planes * B*D
    for (size_t idx = i; idx < HN; idx += stride) { h0[idx] = 0; h1[idx] = 0; }
    for (size_t idx = i; idx < 2 * TQ; idx += stride) cnt[idx] = 0;
}

// Persistent LSTM layer. 256 blocks (1/CU), block p owns h-cols [4p,4p+4).
// LDS: weight slice [2048 x 16] as hi/lo bf16 (split-bf16 MFMA, 3 products
// per pair -> ~fp32 accuracy). One grid barrier per timestep; h double-buffered.
__global__ __launch_bounds__(NTHR, 1) void lstm_layer_kernel(
    const u16* __restrict__ in_hi, const u16* __restrict__ in_lo,  // [B][T][D]
    const float* __restrict__ W,    // [2048][4096]
    const float* __restrict__ bias, // [4096]
    const int* __restrict__ lens,   // [B]
    u16* __restrict__ hbuf,         // [2 buf][2 plane][B*D]
    unsigned* __restrict__ cnt,     // [T]
    u16* __restrict__ out_hi, u16* __restrict__ out_lo,  // layer0: bf16 planes
    float* __restrict__ out_f32,    // layer1: d_out
    float* __restrict__ hc_out,     // layer1: d_out + B*T*D (h1 then c1)
    int is_last)
{
    __shared__ u16 wt[2][16][2056];   // [plane][n][k], pad 2056 -> 2-way bank alias (free)
    __shared__ float red[4][32][16];  // per-wave partial z

    const int tid = threadIdx.x;
    const int blk = blockIdx.x;

    // ---- stage & split weight slice into LDS (once) ----
    for (int idx = tid; idx < 2048 * 16; idx += NTHR) {
        int k = idx >> 4, n = idx & 15;
        int c = n >> 2, g = n & 3;                 // n = c*4 + g; g: 0=i 1=j 2=f 3=o
        int gcol = g * DQ + 4 * blk + c;
        float w = W[(size_t)k * (4 * DQ) + gcol];
        u16 wh = f2bf(w);
        wt[0][n][k] = wh;
        wt[1][n][k] = f2bf(w - bf2f(wh));
    }

    // ---- gate-thread persistent state (tid < 128: thread = (b, c)) ----
    const int gb = tid >> 2;
    const int gc = tid & 3;
    const int hcol = 4 * blk + gc;
    float c_state = 0.f, h_state = 0.f;
    float bi = 0.f, bj = 0.f, bf_ = 0.f, bo = 0.f;
    int mylen = 0;
    if (tid < 128) {
        bi  = bias[0 * DQ + hcol];
        bj  = bias[1 * DQ + hcol];
        bf_ = bias[2 * DQ + hcol];
        bo  = bias[3 * DQ + hcol];
        mylen = lens[gb];
    }

    const int wave = tid >> 6;
    const int lane = tid & 63;
    const int frow = lane & 15;   // A: batch row (within 16); B: col n; D: col n
    const int quad = lane >> 4;

    __syncthreads();

    for (int t = 0; t < TQ; ++t) {
        // ---- MFMA partial z over this wave's K range (wave w: k in [512w,512w+512)) ----
        f4v acc0 = {0.f, 0.f, 0.f, 0.f};
        f4v acc1 = {0.f, 0.f, 0.f, 0.f};

        const u16 *ah, *al;
        size_t rstride;
        int ksrc;
        if (wave < 2) {            // x part (k < 1024)
            size_t base = (size_t)t * DQ;
            ah = in_hi + base; al = in_lo + base;
            rstride = (size_t)TQ * DQ;
            ksrc = wave * 512;
        } else {                   // h part (k >= 1024), read h_{t-1} buffer
            int pb = (t & 1) ^ 1;
            ah = hbuf + (size_t)(pb * 2 + 0) * (BQ * DQ);
            al = hbuf + (size_t)(pb * 2 + 1) * (BQ * DQ);
            rstride = DQ;
            ksrc = (wave - 2) * 512;
        }
        const int kglob = wave * 512;

        #pragma unroll 4
        for (int s = 0; s < 16; ++s) {
            const int koff = s * 32 + quad * 8;
            const u16* p0h = ah + (size_t)frow * rstride + ksrc + koff;
            const u16* p0l = al + (size_t)frow * rstride + ksrc + koff;
            s8v a0h = *(const s8v*)p0h;
            s8v a0l = *(const s8v*)p0l;
            s8v a1h = *(const s8v*)(p0h + 16 * rstride);
            s8v a1l = *(const s8v*)(p0l + 16 * rstride);
            s8v bh = *(const s8v*)&wt[0][frow][kglob + koff];
            s8v bl = *(const s8v*)&wt[1][frow][kglob + koff];
            acc0 = __builtin_amdgcn_mfma_f32_16x16x32_bf16(a0h, bh, acc0, 0, 0, 0);
            acc1 = __builtin_amdgcn_mfma_f32_16x16x32_bf16(a1h, bh, acc1, 0, 0, 0);
            acc0 = __builtin_amdgcn_mfma_f32_16x16x32_bf16(a0l, bh, acc0, 0, 0, 0);
            acc1 = __builtin_amdgcn_mfma_f32_16x16x32_bf16(a1l, bh, acc1, 0, 0, 0);
            acc0 = __builtin_amdgcn_mfma_f32_16x16x32_bf16(a0h, bl, acc0, 0, 0, 0);
            acc1 = __builtin_amdgcn_mfma_f32_16x16x32_bf16(a1h, bl, acc1, 0, 0, 0);
        }
        // D layout: col = lane&15, row = quad*4 + reg
        #pragma unroll
        for (int r = 0; r < 4; ++r) {
            red[wave][quad * 4 + r][frow] = acc0[r];
            red[wave][16 + quad * 4 + r][frow] = acc1[r];
        }
        __syncthreads();

        // ---- gates (threads 0..127) ----
        if (tid < 128) {
            float z[4];
            #pragma unroll
            for (int g = 0; g < 4; ++g) {
                int n = gc * 4 + g;
                z[g] = red[0][gb][n] + red[1][gb][n] + red[2][gb][n] + red[3][gb][n];
            }
            float zi = z[0] + bi, zj = z[1] + bj, zf = z[2] + bf_, zo = z[3] + bo;
            float si = 1.f / (1.f + __expf(-zi));
            float sf = 1.f / (1.f + __expf(-(zf + 1.0f)));  // forget_bias
            float so = 1.f / (1.f + __expf(-zo));
            float cn = sf * c_state + si * tanhf(zj);
            float hn = so * tanhf(cn);
            bool m = (t < mylen);
            float hk = m ? hn : h_state;
            float ck = m ? cn : c_state;
            float ho = m ? hn : 0.f;
            h_state = hk; c_state = ck;

            u16 hh = f2bf(hk);
            u16 hl = f2bf(hk - bf2f(hh));
            int pb = t & 1;
            hbuf[(size_t)(pb * 2 + 0) * (BQ * DQ) + gb * DQ + hcol] = hh;
            hbuf[(size_t)(pb * 2 + 1) * (BQ * DQ) + gb * DQ + hcol] = hl;

            size_t oidx = ((size_t)gb * TQ + t) * DQ + hcol;
            if (is_last) {
                out_f32[oidx] = ho;
            } else {
                u16 oh = f2bf(ho);
                out_hi[oidx] = oh;
                out_lo[oidx] = f2bf(ho - bf2f(oh));
            }
        }

        // ---- grid barrier (also guards red[] reuse) ----
        __syncthreads();
        if (t < TQ - 1) {
            if (tid == 0) {
                __threadfence();                 // release (agent scope: L2 wb)
                atomicAdd(&cnt[t], 1u);
                while (__hip_atomic_load(&cnt[t], __ATOMIC_RELAXED,
                                         __HIP_MEMORY_SCOPE_AGENT) < (unsigned)gridDim.x) { }
                __threadfence();                 // acquire (L1/L2 inv)
            }
            __syncthreads();
        }
    }

    if (is_last && tid < 128) {
        hc_out[gb * DQ + hcol] = h_state;                 // h1 (frozen)
        hc_out[BQ * DQ + gb * DQ + hcol] = c_state;       // c1 (frozen)
    }
}

extern "C" void kernel_launch(void* const* d_in, const int* in_sizes, int n_in,
                              void* d_out, int out_size, void* d_ws, size_t ws_size,
                              hipStream_t stream) {
    const float* x    = (const float*)d_in[0];
    const int*   lens = (const int*)d_in[1];
    const float* W0   = (const float*)d_in[2];
    const float* b0   = (const float*)d_in[3];
    const float* W1   = (const float*)d_in[4];
    const float* b1   = (const float*)d_in[5];
    float* out = (float*)d_out;

    const size_t N = (size_t)BQ * TQ * DQ;      // 16,777,216
    u16* x_hi  = (u16*)d_ws;
    u16* x_lo  = x_hi + N;
    u16* o0_hi = x_lo + N;
    u16* o0_lo = o0_hi + N;
    u16* h0    = o0_lo + N;                     // 4*B*D ushorts
    u16* h1    = h0 + 4 * (size_t)BQ * DQ;
    unsigned* cnt = (unsigned*)(h1 + 4 * (size_t)BQ * DQ);  // 2*T counters
    // ws needed: ~134.75 MB

    init_kernel<<<2048, 256, 0, stream>>>(x, x_hi, x_lo, h0, h1, cnt);

    lstm_layer_kernel<<<NBLK, NTHR, 0, stream>>>(
        x_hi, x_lo, W0, b0, lens, h0, cnt,
        o0_hi, o0_lo, nullptr, nullptr, 0);

    lstm_layer_kernel<<<NBLK, NTHR, 0, stream>>>(
        o0_hi, o0_lo, W1, b1, lens, h1, cnt + TQ,
        nullptr, nullptr, out, out + N, 1);
}

// Round 2
// 15037.709 us; speedup vs baseline: 2.0011x; 2.0011x over previous
//
#include <hip/hip_runtime.h>
#include <hip/hip_bf16.h>

typedef unsigned short u16;
typedef unsigned int u32;
typedef unsigned long long u64;
typedef short s8v __attribute__((ext_vector_type(8)));
typedef float f4v __attribute__((ext_vector_type(4)));

#define BQ 32
#define TQ 512
#define DQ 1024
#define NBLK 256
#define NTHR 256
#define NGRP 8
#define NSUB (NBLK / NGRP)

__device__ __host__ inline u16 f2bf(float f) {
    union { float f; unsigned u; } v; v.f = f;
    unsigned r = v.u + 0x7fffu + ((v.u >> 16) & 1u);  // RNE
    return (u16)(r >> 16);
}
__device__ __host__ inline float bf2f(u16 u) {
    union { unsigned u; float f; } v; v.u = ((unsigned)u) << 16;
    return v.f;
}

// Pre-split x into bf16 hi/lo planes; zero h32 buffers + barrier counters.
__global__ void init_kernel(const float* __restrict__ x,
                            u16* __restrict__ x_hi, u16* __restrict__ x_lo,
                            u32* __restrict__ zero32, size_t nzero) {
    size_t i = (size_t)blockIdx.x * blockDim.x + threadIdx.x;
    size_t stride = (size_t)gridDim.x * blockDim.x;
    const size_t N = (size_t)BQ * TQ * DQ;
    for (size_t idx = i; idx < N; idx += stride) {
        float v = x[idx];
        u16 hh = f2bf(v);
        x_hi[idx] = hh;
        x_lo[idx] = f2bf(v - bf2f(hh));
    }
    for (size_t idx = i; idx < nzero; idx += stride) zero32[idx] = 0;
}

__device__ inline void unpack_h(u64 q0, u64 q1, u64 q2, u64 q3, s8v& hi, s8v& lo) {
    union { u32 u[4]; s8v v; } H, L;
    u32 w0, w1;
    w0 = (u32)q0; w1 = (u32)(q0 >> 32);
    H.u[0] = (w0 >> 16) | (w1 & 0xffff0000u); L.u[0] = (w0 & 0xffffu) | (w1 << 16);
    w0 = (u32)q1; w1 = (u32)(q1 >> 32);
    H.u[1] = (w0 >> 16) | (w1 & 0xffff0000u); L.u[1] = (w0 & 0xffffu) | (w1 << 16);
    w0 = (u32)q2; w1 = (u32)(q2 >> 32);
    H.u[2] = (w0 >> 16) | (w1 & 0xffff0000u); L.u[2] = (w0 & 0xffffu) | (w1 << 16);
    w0 = (u32)q3; w1 = (u32)(q3 >> 32);
    H.u[3] = (w0 >> 16) | (w1 & 0xffff0000u); L.u[3] = (w0 & 0xffffu) | (w1 << 16);
    hi = H.v; lo = L.v;
}

// Persistent LSTM layer. 256 blocks (1/CU), block p owns h-cols [4p,4p+4).
// Cross-block h travels as packed (hi<<16|lo) u32 agent-scope atomics that
// bypass L1/L2 -> NO threadfence (no wbl2/inv) anywhere. x/weights stay on the
// plain cached path (read-only, L2 never invalidated). Two-level spin barrier.
__global__ __launch_bounds__(NTHR, 1) void lstm_layer_kernel(
    const u16* __restrict__ in_hi, const u16* __restrict__ in_lo,  // [B][T][D]
    const float* __restrict__ W,    // [2048][4096]
    const float* __restrict__ bias, // [4096]
    const int* __restrict__ lens,   // [B]
    u32* __restrict__ h32,          // [2 parity][B*D] packed hi|lo
    u32* __restrict__ subc,         // [T][8] stride 16
    u32* __restrict__ topc,         // [T] stride 16
    u16* __restrict__ out_hi, u16* __restrict__ out_lo,  // layer0 out planes
    float* __restrict__ out_f32,    // layer1: d_out
    float* __restrict__ hc_out,     // layer1: d_out + B*T*D (h1 then c1)
    int is_last)
{
    __shared__ u16 wt[2][16][2056];   // [plane][n][k]
    __shared__ float red[4][32][16];  // per-wave partial z

    const int tid = threadIdx.x;
    const int blk = blockIdx.x;
    const int grp = blk & (NGRP - 1);

    // ---- stage & split weight slice into LDS (once) ----
    for (int idx = tid; idx < 2048 * 16; idx += NTHR) {
        int k = idx >> 4, n = idx & 15;
        int c = n >> 2, g = n & 3;                 // n = c*4 + g
        int gcol = g * DQ + 4 * blk + c;
        float w = W[(size_t)k * (4 * DQ) + gcol];
        u16 wh = f2bf(w);
        wt[0][n][k] = wh;
        wt[1][n][k] = f2bf(w - bf2f(wh));
    }

    // ---- gate-thread persistent state (tid < 128: thread = (b, c)) ----
    const int gb = tid >> 2;
    const int gc = tid & 3;
    const int hcol = 4 * blk + gc;
    float c_state = 0.f, h_state = 0.f;
    float bi = 0.f, bj = 0.f, bf_ = 0.f, bo = 0.f;
    int mylen = 0;
    if (tid < 128) {
        bi  = bias[0 * DQ + hcol];
        bj  = bias[1 * DQ + hcol];
        bf_ = bias[2 * DQ + hcol];
        bo  = bias[3 * DQ + hcol];
        mylen = lens[gb];
    }

    const int wave = tid >> 6;
    const int lane = tid & 63;
    const int frow = lane & 15;
    const int quad = lane >> 4;

    __syncthreads();

    for (int t = 0; t < TQ; ++t) {
        f4v acc0 = {0.f, 0.f, 0.f, 0.f};
        f4v acc1 = {0.f, 0.f, 0.f, 0.f};

        if (wave < 2) {
            // ---- x part: plain cached loads (read-only, L2 stays warm) ----
            const int ksrc = wave * 512;
            const u16* ah = in_hi + (size_t)t * DQ + ksrc;
            const u16* al = in_lo + (size_t)t * DQ + ksrc;
            const size_t rstride = (size_t)TQ * DQ;
            #pragma unroll 4
            for (int s = 0; s < 16; ++s) {
                const int koff = s * 32 + quad * 8;
                const u16* p0h = ah + (size_t)frow * rstride + koff;
                const u16* p0l = al + (size_t)frow * rstride + koff;
                s8v a0h = *(const s8v*)p0h;
                s8v a0l = *(const s8v*)p0l;
                s8v a1h = *(const s8v*)(p0h + 16 * rstride);
                s8v a1l = *(const s8v*)(p0l + 16 * rstride);
                s8v bh = *(const s8v*)&wt[0][frow][ksrc + koff];
                s8v bl = *(const s8v*)&wt[1][frow][ksrc + koff];
                acc0 = __builtin_amdgcn_mfma_f32_16x16x32_bf16(a0h, bh, acc0, 0, 0, 0);
                acc1 = __builtin_amdgcn_mfma_f32_16x16x32_bf16(a1h, bh, acc1, 0, 0, 0);
                acc0 = __builtin_amdgcn_mfma_f32_16x16x32_bf16(a0l, bh, acc0, 0, 0, 0);
                acc1 = __builtin_amdgcn_mfma_f32_16x16x32_bf16(a1l, bh, acc1, 0, 0, 0);
                acc0 = __builtin_amdgcn_mfma_f32_16x16x32_bf16(a0h, bl, acc0, 0, 0, 0);
                acc1 = __builtin_amdgcn_mfma_f32_16x16x32_bf16(a1h, bl, acc1, 0, 0, 0);
            }
        } else {
            // ---- h part: agent-scope loads bypass L1/L2 -> always fresh ----
            const int ksrc = (wave - 2) * 512;
            u32* hp = h32 + (size_t)((t & 1) ^ 1) * (BQ * DQ);
            #pragma unroll 2
            for (int s = 0; s < 16; ++s) {
                const int koff = s * 32 + quad * 8;
                const int col = ksrc + koff;
                u64* p0 = (u64*)(hp + (size_t)frow * DQ + col);
                u64* p1 = (u64*)(hp + (size_t)(frow + 16) * DQ + col);
                u64 q00 = __hip_atomic_load(p0 + 0, __ATOMIC_RELAXED, __HIP_MEMORY_SCOPE_AGENT);
                u64 q01 = __hip_atomic_load(p0 + 1, __ATOMIC_RELAXED, __HIP_MEMORY_SCOPE_AGENT);
                u64 q02 = __hip_atomic_load(p0 + 2, __ATOMIC_RELAXED, __HIP_MEMORY_SCOPE_AGENT);
                u64 q03 = __hip_atomic_load(p0 + 3, __ATOMIC_RELAXED, __HIP_MEMORY_SCOPE_AGENT);
                u64 q10 = __hip_atomic_load(p1 + 0, __ATOMIC_RELAXED, __HIP_MEMORY_SCOPE_AGENT);
                u64 q11 = __hip_atomic_load(p1 + 1, __ATOMIC_RELAXED, __HIP_MEMORY_SCOPE_AGENT);
                u64 q12 = __hip_atomic_load(p1 + 2, __ATOMIC_RELAXED, __HIP_MEMORY_SCOPE_AGENT);
                u64 q13 = __hip_atomic_load(p1 + 3, __ATOMIC_RELAXED, __HIP_MEMORY_SCOPE_AGENT);
                s8v a0h, a0l, a1h, a1l;
                unpack_h(q00, q01, q02, q03, a0h, a0l);
                unpack_h(q10, q11, q12, q13, a1h, a1l);
                s8v bh = *(const s8v*)&wt[0][frow][1024 + ksrc + koff];
                s8v bl = *(const s8v*)&wt[1][frow][1024 + ksrc + koff];
                acc0 = __builtin_amdgcn_mfma_f32_16x16x32_bf16(a0h, bh, acc0, 0, 0, 0);
                acc1 = __builtin_amdgcn_mfma_f32_16x16x32_bf16(a1h, bh, acc1, 0, 0, 0);
                acc0 = __builtin_amdgcn_mfma_f32_16x16x32_bf16(a0l, bh, acc0, 0, 0, 0);
                acc1 = __builtin_amdgcn_mfma_f32_16x16x32_bf16(a1l, bh, acc1, 0, 0, 0);
                acc0 = __builtin_amdgcn_mfma_f32_16x16x32_bf16(a0h, bl, acc0, 0, 0, 0);
                acc1 = __builtin_amdgcn_mfma_f32_16x16x32_bf16(a1h, bl, acc1, 0, 0, 0);
            }
        }
        // D layout: col = lane&15, row = quad*4 + reg
        #pragma unroll
        for (int r = 0; r < 4; ++r) {
            red[wave][quad * 4 + r][frow] = acc0[r];
            red[wave][16 + quad * 4 + r][frow] = acc1[r];
        }
        __syncthreads();

        // ---- gates (threads 0..127) ----
        if (tid < 128) {
            float z[4];
            #pragma unroll
            for (int g = 0; g < 4; ++g) {
                int n = gc * 4 + g;
                z[g] = red[0][gb][n] + red[1][gb][n] + red[2][gb][n] + red[3][gb][n];
            }
            float zi = z[0] + bi, zj = z[1] + bj, zf = z[2] + bf_, zo = z[3] + bo;
            float si = 1.f / (1.f + __expf(-zi));
            float sf = 1.f / (1.f + __expf(-(zf + 1.0f)));  // forget_bias
            float so = 1.f / (1.f + __expf(-zo));
            float cn = sf * c_state + si * tanhf(zj);
            float hn = so * tanhf(cn);
            bool m = (t < mylen);
            float hk = m ? hn : h_state;
            float ck = m ? cn : c_state;
            float ho = m ? hn : 0.f;
            h_state = hk; c_state = ck;

            u16 hh = f2bf(hk);
            u16 hl = f2bf(hk - bf2f(hh));
            u32 packed = ((u32)hh << 16) | (u32)hl;
            __hip_atomic_store(h32 + (size_t)(t & 1) * (BQ * DQ) + gb * DQ + hcol,
                               packed, __ATOMIC_RELAXED, __HIP_MEMORY_SCOPE_AGENT);

            size_t oidx = ((size_t)gb * TQ + t) * DQ + hcol;
            if (is_last) {
                out_f32[oidx] = ho;
            } else {
                u16 oh = f2bf(ho);
                out_hi[oidx] = oh;
                out_lo[oidx] = f2bf(ho - bf2f(oh));
            }
        }

        // ---- release: h stores drained to coherence point, then 2-level barrier ----
        asm volatile("s_waitcnt vmcnt(0)" ::: "memory");
        __syncthreads();
        if (t < TQ - 1) {
            if (tid == 0) {
                u32 old = atomicAdd(&subc[(t * NGRP + grp) * 16], 1u);
                if (old == NSUB - 1) atomicAdd(&topc[t * 16], 1u);
                while (__hip_atomic_load(&topc[t * 16], __ATOMIC_RELAXED,
                                         __HIP_MEMORY_SCOPE_AGENT) < NGRP) { }
            }
            __syncthreads();
        }
    }

    if (is_last && tid < 128) {
        hc_out[gb * DQ + hcol] = h_state;                 // h1 (frozen)
        hc_out[BQ * DQ + gb * DQ + hcol] = c_state;       // c1 (frozen)
    }
}

extern "C" void kernel_launch(void* const* d_in, const int* in_sizes, int n_in,
                              void* d_out, int out_size, void* d_ws, size_t ws_size,
                              hipStream_t stream) {
    const float* x    = (const float*)d_in[0];
    const int*   lens = (const int*)d_in[1];
    const float* W0   = (const float*)d_in[2];
    const float* b0   = (const float*)d_in[3];
    const float* W1   = (const float*)d_in[4];
    const float* b1   = (const float*)d_in[5];
    float* out = (float*)d_out;

    const size_t N = (size_t)BQ * TQ * DQ;      // 16,777,216
    u16* x_hi  = (u16*)d_ws;
    u16* x_lo  = x_hi + N;
    u16* o0_hi = x_lo + N;
    u16* o0_lo = o0_hi + N;
    u32* h32   = (u32*)(o0_lo + N);             // [2 layer][2 parity][B*D]
    const size_t HN = 2 * (size_t)BQ * DQ;      // per-layer h32 elems (2 parities)
    u32* cnt   = h32 + 2 * HN;                  // counters, contiguous after h32
    const size_t CNT_PER_LAYER = (size_t)TQ * NGRP * 16 + (size_t)TQ * 16;
    const size_t nzero = 2 * HN + 2 * CNT_PER_LAYER;

    init_kernel<<<2048, 256, 0, stream>>>(x, x_hi, x_lo, h32, nzero);

    u32* sub0 = cnt;
    u32* top0 = sub0 + (size_t)TQ * NGRP * 16;
    u32* sub1 = top0 + (size_t)TQ * 16;
    u32* top1 = sub1 + (size_t)TQ * NGRP * 16;

    lstm_layer_kernel<<<NBLK, NTHR, 0, stream>>>(
        x_hi, x_lo, W0, b0, lens, h32, sub0, top0,
        o0_hi, o0_lo, nullptr, nullptr, 0);

    lstm_layer_kernel<<<NBLK, NTHR, 0, stream>>>(
        o0_hi, o0_lo, W1, b1, lens, h32 + HN, sub1, top1,
        nullptr, nullptr, out, out + N, 1);
}

// Round 4
// 8443.532 us; speedup vs baseline: 3.5638x; 1.7810x over previous
//
#include <hip/hip_runtime.h>
#include <hip/hip_bf16.h>

typedef unsigned short u16;
typedef unsigned int u32;
typedef unsigned long long u64;
typedef short s8v __attribute__((ext_vector_type(8)));
typedef float f4v __attribute__((ext_vector_type(4)));

#define BQ 32
#define TQ 512
#define DQ 1024
#define CHUNK 128
#define NCHUNK (TQ / CHUNK)
#define NTHR 256
#define NBLK_R 256
#define NGRP 16
#define NSUB (NBLK_R / NGRP)

__device__ __host__ inline u16 f2bf(float f) {
    union { float f; unsigned u; } v; v.f = f;
    unsigned r = v.u + 0x7fffu + ((v.u >> 16) & 1u);  // RNE
    return (u16)(r >> 16);
}
__device__ __host__ inline float bf2f(u16 u) {
    union { unsigned u; float f; } v; v.u = ((unsigned)u) << 16;
    return v.f;
}

// Zero h32 buffers, state, and barrier counters (one contiguous span).
__global__ void init_kernel(u32* __restrict__ zero32, size_t nzero) {
    size_t i = (size_t)blockIdx.x * blockDim.x + threadIdx.x;
    size_t stride = (size_t)gridDim.x * blockDim.x;
    for (size_t idx = i; idx < nzero; idx += stride) zero32[idx] = 0;
}

// Unpack 8 packed (hi<<16|lo) u32 cols into hi/lo bf16x8 fragments.
__device__ inline void unpack_pk(uint4 A, uint4 B, s8v& hi, s8v& lo) {
    union { u32 u[4]; s8v v; } H, L;
    H.u[0] = (A.x >> 16) | (A.y & 0xffff0000u); L.u[0] = (A.x & 0xffffu) | (A.y << 16);
    H.u[1] = (A.z >> 16) | (A.w & 0xffff0000u); L.u[1] = (A.z & 0xffffu) | (A.w << 16);
    H.u[2] = (B.x >> 16) | (B.y & 0xffff0000u); L.u[2] = (B.x & 0xffffu) | (B.y << 16);
    H.u[3] = (B.z >> 16) | (B.w & 0xffff0000u); L.u[3] = (B.z & 0xffffu) | (B.w << 16);
    hi = H.v; lo = L.v;
}

// ---------------------------------------------------------------------------
// xproj GEMM: zx[b*CHUNK + tl][4096] = in[b][t0+tl][:] @ W[0:1024][:] + bias
// Split-bf16 triple product. 128x128 tile, 4 waves 2x2, BK=32.
// Input: f32 (layer 0) or packed hi|lo u32 plane (layer 1 = out0).
// ---------------------------------------------------------------------------
__global__ __launch_bounds__(NTHR) void xproj_gemm_kernel(
    const float* __restrict__ in_f32,
    const u32* __restrict__ in_pk,
    const float* __restrict__ W,    // [2048][4096], rows [0,1024) used
    const float* __restrict__ bias, // [4096]
    float* __restrict__ zx,         // [B*CHUNK][4096]
    int t0)
{
    __shared__ u16 As[2][128][40];
    __shared__ u16 Bs[2][128][40];

    const int tid = threadIdx.x;
    const int bm = blockIdx.x & 31;
    const int bn = blockIdx.x >> 5;

    const int wv = tid >> 6;
    const int wm = wv >> 1, wn = wv & 1;
    const int lane = tid & 63;
    const int frow = lane & 15;
    const int quad = lane >> 4;

    const int am = tid >> 1;
    const int akh = (tid & 1) * 16;
    const int amg = bm * 128 + am;
    const int ab = amg >> 7;
    const int atl = amg & 127;
    const size_t arow = ((size_t)ab * TQ + t0 + atl) * DQ;

    const int bk = tid >> 3;
    const int bng = (tid & 7) * 16;

    f4v acc[4][4];
    #pragma unroll
    for (int i = 0; i < 4; ++i)
        #pragma unroll
        for (int j = 0; j < 4; ++j) acc[i][j] = (f4v){0.f, 0.f, 0.f, 0.f};

    for (int kt = 0; kt < 32; ++kt) {
        const int k0 = kt * 32;
        if (in_f32) {
            const float* src = in_f32 + arow + k0 + akh;
            #pragma unroll
            for (int j4 = 0; j4 < 4; ++j4) {
                float4 v = ((const float4*)src)[j4];
                float vv[4] = {v.x, v.y, v.z, v.w};
                #pragma unroll
                for (int e = 0; e < 4; ++e) {
                    u16 hh = f2bf(vv[e]);
                    As[0][am][akh + j4 * 4 + e] = hh;
                    As[1][am][akh + j4 * 4 + e] = f2bf(vv[e] - bf2f(hh));
                }
            }
        } else {
            const u32* src = in_pk + arow + k0 + akh;
            #pragma unroll
            for (int j4 = 0; j4 < 4; ++j4) {
                uint4 v = ((const uint4*)src)[j4];
                u32 vv[4] = {v.x, v.y, v.z, v.w};
                #pragma unroll
                for (int e = 0; e < 4; ++e) {
                    As[0][am][akh + j4 * 4 + e] = (u16)(vv[e] >> 16);
                    As[1][am][akh + j4 * 4 + e] = (u16)(vv[e] & 0xffffu);
                }
            }
        }
        {
            const float* wsrc = W + (size_t)(k0 + bk) * (4 * DQ) + bn * 128 + bng;
            #pragma unroll
            for (int j4 = 0; j4 < 4; ++j4) {
                float4 v = ((const float4*)wsrc)[j4];
                float vv[4] = {v.x, v.y, v.z, v.w};
                #pragma unroll
                for (int e = 0; e < 4; ++e) {
                    u16 hh = f2bf(vv[e]);
                    int n = bng + j4 * 4 + e;
                    Bs[0][n][bk] = hh;
                    Bs[1][n][bk] = f2bf(vv[e] - bf2f(hh));
                }
            }
        }
        __syncthreads();

        s8v ah[4], al[4], bh[4], bl[4];
        #pragma unroll
        for (int mt = 0; mt < 4; ++mt) {
            ah[mt] = *(const s8v*)&As[0][wm * 64 + mt * 16 + frow][quad * 8];
            al[mt] = *(const s8v*)&As[1][wm * 64 + mt * 16 + frow][quad * 8];
        }
        #pragma unroll
        for (int nt = 0; nt < 4; ++nt) {
            bh[nt] = *(const s8v*)&Bs[0][wn * 64 + nt * 16 + frow][quad * 8];
            bl[nt] = *(const s8v*)&Bs[1][wn * 64 + nt * 16 + frow][quad * 8];
        }
        #pragma unroll
        for (int mt = 0; mt < 4; ++mt)
            #pragma unroll
            for (int nt = 0; nt < 4; ++nt) {
                acc[mt][nt] = __builtin_amdgcn_mfma_f32_16x16x32_bf16(ah[mt], bh[nt], acc[mt][nt], 0, 0, 0);
                acc[mt][nt] = __builtin_amdgcn_mfma_f32_16x16x32_bf16(al[mt], bh[nt], acc[mt][nt], 0, 0, 0);
                acc[mt][nt] = __builtin_amdgcn_mfma_f32_16x16x32_bf16(ah[mt], bl[nt], acc[mt][nt], 0, 0, 0);
            }
        __syncthreads();
    }

    float bv[4];
    #pragma unroll
    for (int nt = 0; nt < 4; ++nt) bv[nt] = bias[bn * 128 + wn * 64 + nt * 16 + frow];
    #pragma unroll
    for (int mt = 0; mt < 4; ++mt) {
        #pragma unroll
        for (int nt = 0; nt < 4; ++nt) {
            int col = bn * 128 + wn * 64 + nt * 16 + frow;
            #pragma unroll
            for (int r = 0; r < 4; ++r) {
                int row = bm * 128 + wm * 64 + mt * 16 + quad * 4 + r;
                zx[(size_t)row * (4 * DQ) + col] = acc[mt][nt][r] + bv[nt];
            }
        }
    }
}

// ---------------------------------------------------------------------------
// Recurrence: 256 blocks = 2 batch-groups (16 rows) x 128 col-groups (8 hcols).
// h travels as packed u32 via uncached stores (atomic relaxed agent) and
// uncached 16B asm loads (sc0 sc1) -> 16 MB/step aggregate, 1M reqs/step.
// Wh slice (K=1024, 32 gate cols, split-bf16) in LDS. zx precomputed.
// ---------------------------------------------------------------------------
__global__ __launch_bounds__(NTHR, 1) void lstm_rec_kernel(
    const float* __restrict__ zx,   // [B*CHUNK][4096], bias folded in
    const float* __restrict__ W,    // [2048][4096], rows [1024,2048) used
    const int* __restrict__ lens,
    u32* __restrict__ h32,          // [2 parity][B*DQ] packed hi|lo
    u32* __restrict__ subc,         // [T][NGRP] stride 16
    u32* __restrict__ topc,         // [T] stride 16
    float* __restrict__ state_h,    // [B*DQ]
    float* __restrict__ state_c,    // [B*DQ]
    u32* __restrict__ out_pk,       // layer0 out, packed hi|lo
    float* __restrict__ out_f32,    // layer1: d_out
    float* __restrict__ hc_out,     // layer1: d_out + B*T*DQ (h1 then c1)
    int t0, int is_last)
{
    __shared__ u16 wt[2][32][1032];
    __shared__ float red[4][16][36];

    const int tid = threadIdx.x;
    const int blk = blockIdx.x;
    const int bg = blk & 1;          // batch-group (rows bg*16 .. +16)
    const int cg = blk >> 1;         // col-group 0..127 (hcols cg*8 .. +8)
    const int grp = blk & (NGRP - 1);

    for (int idx = tid; idx < 32 * 1024; idx += NTHR) {
        int n = idx & 31, k = idx >> 5;
        int c = n >> 2, g = n & 3;
        float w = W[(size_t)(DQ + k) * (4 * DQ) + g * DQ + cg * 8 + c];
        u16 wh = f2bf(w);
        wt[0][n][k] = wh;
        wt[1][n][k] = f2bf(w - bf2f(wh));
    }

    const int gb_l = tid >> 3;       // local batch 0..15
    const int gc = tid & 7;          // local hcol 0..7
    const int b_g = bg * 16 + gb_l;
    const int hcol = cg * 8 + gc;
    float c_state = 0.f, h_state = 0.f;
    int mylen = 0;
    if (tid < 128) {
        mylen = lens[b_g];
        h_state = state_h[(size_t)b_g * DQ + hcol];
        c_state = state_c[(size_t)b_g * DQ + hcol];
    }

    const int wave = tid >> 6;
    const int lane = tid & 63;
    const int frow = lane & 15;
    const int quad = lane >> 4;
    const int ksrc = wave * 256;     // K-split across 4 waves
    const u32* hrow = h32 + (size_t)(bg * 16 + frow) * DQ + ksrc + quad * 8;

    __syncthreads();

    const int tend = t0 + CHUNK;
    for (int t = t0; t < tend; ++t) {
        const u32* hp = hrow + (size_t)((t & 1) ^ 1) * (BQ * DQ);
        uint4 q[16];
        asm volatile(
            "global_load_dwordx4 %0, %16, off sc0 sc1\n\t"
            "global_load_dwordx4 %1, %16, off offset:16 sc0 sc1\n\t"
            "global_load_dwordx4 %2, %16, off offset:128 sc0 sc1\n\t"
            "global_load_dwordx4 %3, %16, off offset:144 sc0 sc1\n\t"
            "global_load_dwordx4 %4, %16, off offset:256 sc0 sc1\n\t"
            "global_load_dwordx4 %5, %16, off offset:272 sc0 sc1\n\t"
            "global_load_dwordx4 %6, %16, off offset:384 sc0 sc1\n\t"
            "global_load_dwordx4 %7, %16, off offset:400 sc0 sc1\n\t"
            "global_load_dwordx4 %8, %16, off offset:512 sc0 sc1\n\t"
            "global_load_dwordx4 %9, %16, off offset:528 sc0 sc1\n\t"
            "global_load_dwordx4 %10, %16, off offset:640 sc0 sc1\n\t"
            "global_load_dwordx4 %11, %16, off offset:656 sc0 sc1\n\t"
            "global_load_dwordx4 %12, %16, off offset:768 sc0 sc1\n\t"
            "global_load_dwordx4 %13, %16, off offset:784 sc0 sc1\n\t"
            "global_load_dwordx4 %14, %16, off offset:896 sc0 sc1\n\t"
            "global_load_dwordx4 %15, %16, off offset:912 sc0 sc1\n\t"
            "s_waitcnt vmcnt(0)"
            : "=&v"(q[0]), "=&v"(q[1]), "=&v"(q[2]), "=&v"(q[3]),
              "=&v"(q[4]), "=&v"(q[5]), "=&v"(q[6]), "=&v"(q[7]),
              "=&v"(q[8]), "=&v"(q[9]), "=&v"(q[10]), "=&v"(q[11]),
              "=&v"(q[12]), "=&v"(q[13]), "=&v"(q[14]), "=&v"(q[15])
            : "v"(hp)
            : "memory");

        f4v acc0 = {0.f, 0.f, 0.f, 0.f};
        f4v acc1 = {0.f, 0.f, 0.f, 0.f};
        #pragma unroll
        for (int s = 0; s < 8; ++s) {
            s8v a_h, a_l;
            unpack_pk(q[2 * s], q[2 * s + 1], a_h, a_l);
            const int koff = ksrc + s * 32 + quad * 8;
            s8v b0h = *(const s8v*)&wt[0][frow][koff];
            s8v b0l = *(const s8v*)&wt[1][frow][koff];
            s8v b1h = *(const s8v*)&wt[0][16 + frow][koff];
            s8v b1l = *(const s8v*)&wt[1][16 + frow][koff];
            acc0 = __builtin_amdgcn_mfma_f32_16x16x32_bf16(a_h, b0h, acc0, 0, 0, 0);
            acc1 = __builtin_amdgcn_mfma_f32_16x16x32_bf16(a_h, b1h, acc1, 0, 0, 0);
            acc0 = __builtin_amdgcn_mfma_f32_16x16x32_bf16(a_l, b0h, acc0, 0, 0, 0);
            acc1 = __builtin_amdgcn_mfma_f32_16x16x32_bf16(a_l, b1h, acc1, 0, 0, 0);
            acc0 = __builtin_amdgcn_mfma_f32_16x16x32_bf16(a_h, b0l, acc0, 0, 0, 0);
            acc1 = __builtin_amdgcn_mfma_f32_16x16x32_bf16(a_h, b1l, acc1, 0, 0, 0);
        }
        #pragma unroll
        for (int r = 0; r < 4; ++r) {
            red[wave][quad * 4 + r][frow] = acc0[r];
            red[wave][quad * 4 + r][16 + frow] = acc1[r];
        }

        float zxv[4];
        if (tid < 128) {
            size_t base = ((size_t)b_g * CHUNK + (t - t0)) * (4 * DQ) + hcol;
            #pragma unroll
            for (int g = 0; g < 4; ++g) zxv[g] = zx[base + (size_t)g * DQ];
        }
        __syncthreads();

        if (tid < 128) {
            float z[4];
            #pragma unroll
            for (int g = 0; g < 4; ++g) {
                int n = gc * 4 + g;
                z[g] = red[0][gb_l][n] + red[1][gb_l][n] + red[2][gb_l][n] + red[3][gb_l][n]
                     + zxv[g];
            }
            float si = 1.f / (1.f + __expf(-z[0]));
            float sf = 1.f / (1.f + __expf(-(z[2] + 1.0f)));  // forget_bias
            float so = 1.f / (1.f + __expf(-z[3]));
            float cn = sf * c_state + si * tanhf(z[1]);
            float hn = so * tanhf(cn);
            bool m = (t < mylen);
            float hk = m ? hn : h_state;
            float ck = m ? cn : c_state;
            float ho = m ? hn : 0.f;
            h_state = hk; c_state = ck;

            u16 hh = f2bf(hk);
            u16 hl = f2bf(hk - bf2f(hh));
            u32 packed = ((u32)hh << 16) | (u32)hl;
            __hip_atomic_store(h32 + (size_t)(t & 1) * (BQ * DQ) + (size_t)b_g * DQ + hcol,
                               packed, __ATOMIC_RELAXED, __HIP_MEMORY_SCOPE_AGENT);

            size_t oidx = ((size_t)b_g * TQ + t) * DQ + hcol;
            if (is_last) {
                out_f32[oidx] = ho;
            } else {
                u16 oh = f2bf(ho);
                u16 ol = f2bf(ho - bf2f(oh));
                out_pk[oidx] = ((u32)oh << 16) | (u32)ol;
            }
        }

        asm volatile("s_waitcnt vmcnt(0)" ::: "memory");
        __syncthreads();
        if (t < tend - 1) {
            if (tid == 0) {
                u32 old = atomicAdd(&subc[(t * NGRP + grp) * 16], 1u);
                if (old == NSUB - 1) atomicAdd(&topc[t * 16], 1u);
                while (__hip_atomic_load(&topc[t * 16], __ATOMIC_RELAXED,
                                         __HIP_MEMORY_SCOPE_AGENT) < NGRP) { }
            }
            __syncthreads();
        }
    }

    if (tid < 128) {
        state_h[(size_t)b_g * DQ + hcol] = h_state;
        state_c[(size_t)b_g * DQ + hcol] = c_state;
        if (is_last && tend == TQ) {
            hc_out[(size_t)b_g * DQ + hcol] = h_state;
            hc_out[(size_t)BQ * DQ + (size_t)b_g * DQ + hcol] = c_state;
        }
    }
}

extern "C" void kernel_launch(void* const* d_in, const int* in_sizes, int n_in,
                              void* d_out, int out_size, void* d_ws, size_t ws_size,
                              hipStream_t stream) {
    const float* x    = (const float*)d_in[0];
    const int*   lens = (const int*)d_in[1];
    const float* W0   = (const float*)d_in[2];
    const float* b0   = (const float*)d_in[3];
    const float* W1   = (const float*)d_in[4];
    const float* b1   = (const float*)d_in[5];
    float* out = (float*)d_out;

    const size_t N = (size_t)BQ * TQ * DQ;           // 16,777,216
    const size_t ZXN = (size_t)BQ * CHUNK * 4 * DQ;  // 16,777,216 f32 = 64 MB
    const size_t HD = (size_t)BQ * DQ;               // 32768

    float* zx   = (float*)d_ws;
    u32* o0_pk  = (u32*)(zx + ZXN);
    // zeroed region:
    u32* h32_0  = o0_pk + N;
    u32* h32_1  = h32_0 + 2 * HD;
    float* sh0  = (float*)(h32_1 + 2 * HD);
    float* sc0  = sh0 + HD;
    float* sh1  = sc0 + HD;
    float* sc1  = sh1 + HD;
    u32* sub0   = (u32*)(sc1 + HD);
    u32* top0   = sub0 + (size_t)TQ * NGRP * 16;
    u32* sub1   = top0 + (size_t)TQ * 16;
    u32* top1   = sub1 + (size_t)TQ * NGRP * 16;
    u32* zend   = top1 + (size_t)TQ * 16;
    const size_t nzero = (size_t)(zend - h32_0);

    init_kernel<<<256, 256, 0, stream>>>(h32_0, nzero);

    for (int c = 0; c < NCHUNK; ++c) {
        int t0 = c * CHUNK;
        xproj_gemm_kernel<<<1024, NTHR, 0, stream>>>(x, nullptr, W0, b0, zx, t0);
        lstm_rec_kernel<<<NBLK_R, NTHR, 0, stream>>>(
            zx, W0, lens, h32_0, sub0, top0, sh0, sc0,
            o0_pk, nullptr, nullptr, t0, 0);
    }
    for (int c = 0; c < NCHUNK; ++c) {
        int t0 = c * CHUNK;
        xproj_gemm_kernel<<<1024, NTHR, 0, stream>>>(nullptr, o0_pk, W1, b1, zx, t0);
        lstm_rec_kernel<<<NBLK_R, NTHR, 0, stream>>>(
            zx, W1, lens, h32_1, sub1, top1, sh1, sc1,
            nullptr, out, out + N, t0, 1);
    }
}

// Round 5
// 7436.710 us; speedup vs baseline: 4.0463x; 1.1354x over previous
//
#include <hip/hip_runtime.h>
#include <hip/hip_bf16.h>

typedef unsigned short u16;
typedef unsigned int u32;
typedef unsigned long long u64;
typedef short s8v __attribute__((ext_vector_type(8)));
typedef float f4v __attribute__((ext_vector_type(4)));

#define BQ 32
#define TQ 512
#define DQ 1024
#define CHUNK 128
#define NCHUNK (TQ / CHUNK)
#define NTHR 256
#define NBLK_R 256

__device__ __host__ inline u16 f2bf(float f) {
    union { float f; unsigned u; } v; v.f = f;
    unsigned r = v.u + 0x7fffu + ((v.u >> 16) & 1u);  // RNE
    return (u16)(r >> 16);
}
__device__ __host__ inline float bf2f(u16 u) {
    union { unsigned u; float f; } v; v.u = ((unsigned)u) << 16;
    return v.f;
}

// Zero hh slot 0 and the state/counter span.
__global__ void init_kernel(u32* __restrict__ z0, size_t n0,
                            u32* __restrict__ z1, size_t n1) {
    size_t i = (size_t)blockIdx.x * blockDim.x + threadIdx.x;
    size_t stride = (size_t)gridDim.x * blockDim.x;
    for (size_t idx = i; idx < n0; idx += stride) z0[idx] = 0;
    for (size_t idx = i; idx < n1; idx += stride) z1[idx] = 0;
}

// Unpack 8 packed (hi<<16|lo) u32 cols into hi/lo bf16x8 fragments.
__device__ inline void unpack_pk(uint4 A, uint4 B, s8v& hi, s8v& lo) {
    union { u32 u[4]; s8v v; } H, L;
    H.u[0] = (A.x >> 16) | (A.y & 0xffff0000u); L.u[0] = (A.x & 0xffffu) | (A.y << 16);
    H.u[1] = (A.z >> 16) | (A.w & 0xffff0000u); L.u[1] = (A.z & 0xffffu) | (A.w << 16);
    H.u[2] = (B.x >> 16) | (B.y & 0xffff0000u); L.u[2] = (B.x & 0xffffu) | (B.y << 16);
    H.u[3] = (B.z >> 16) | (B.w & 0xffff0000u); L.u[3] = (B.z & 0xffffu) | (B.w << 16);
    hi = H.v; lo = L.v;
}

// ---------------------------------------------------------------------------
// xproj GEMM: zx[b*CHUNK + tl][4096] = in[b][t0+tl][:] @ W[0:1024][:] + bias
// Split-bf16 triple product. 128x128 tile, 4 waves 2x2, BK=32.
// Input: f32 x (layer 0) or hh history slots (layer 1; out0 = mask * h_keep,
// masking applied at staging with lens).
// ---------------------------------------------------------------------------
__global__ __launch_bounds__(NTHR) void xproj_gemm_kernel(
    const float* __restrict__ in_f32,   // layer0, or null
    const u32* __restrict__ hh,         // [T+1][BQ][DQ] packed hi|lo (layer1)
    const int* __restrict__ lens,
    const float* __restrict__ W,        // [2048][4096], rows [0,1024) used
    const float* __restrict__ bias,     // [4096]
    float* __restrict__ zx,             // [B*CHUNK][4096]
    int t0)
{
    __shared__ u16 As[2][128][40];
    __shared__ u16 Bs[2][128][40];

    const int tid = threadIdx.x;
    const int bm = blockIdx.x & 31;
    const int bn = blockIdx.x >> 5;

    const int wv = tid >> 6;
    const int wm = wv >> 1, wn = wv & 1;
    const int lane = tid & 63;
    const int frow = lane & 15;
    const int quad = lane >> 4;

    const int am = tid >> 1;
    const int akh = (tid & 1) * 16;
    const int amg = bm * 128 + am;
    const int ab = amg >> 7;            // batch
    const int atl = amg & 127;          // t within chunk
    const int at = t0 + atl;

    const int bk = tid >> 3;
    const int bng = (tid & 7) * 16;

    bool arow_live = true;
    size_t arow;
    if (in_f32) {
        arow = ((size_t)ab * TQ + at) * DQ;
    } else {
        arow = ((size_t)(at + 1) * BQ + ab) * DQ;   // hh slot at+1 holds h_at
        arow_live = (at < lens[ab]);
    }

    f4v acc[4][4];
    #pragma unroll
    for (int i = 0; i < 4; ++i)
        #pragma unroll
        for (int j = 0; j < 4; ++j) acc[i][j] = (f4v){0.f, 0.f, 0.f, 0.f};

    for (int kt = 0; kt < 32; ++kt) {
        const int k0 = kt * 32;
        if (in_f32) {
            const float* src = in_f32 + arow + k0 + akh;
            #pragma unroll
            for (int j4 = 0; j4 < 4; ++j4) {
                float4 v = ((const float4*)src)[j4];
                float vv[4] = {v.x, v.y, v.z, v.w};
                #pragma unroll
                for (int e = 0; e < 4; ++e) {
                    u16 hh16 = f2bf(vv[e]);
                    As[0][am][akh + j4 * 4 + e] = hh16;
                    As[1][am][akh + j4 * 4 + e] = f2bf(vv[e] - bf2f(hh16));
                }
            }
        } else {
            const u32* src = hh + arow + k0 + akh;
            #pragma unroll
            for (int j4 = 0; j4 < 4; ++j4) {
                uint4 v = ((const uint4*)src)[j4];
                if (!arow_live) { v.x = v.y = v.z = v.w = 0; }
                u32 vv[4] = {v.x, v.y, v.z, v.w};
                #pragma unroll
                for (int e = 0; e < 4; ++e) {
                    As[0][am][akh + j4 * 4 + e] = (u16)(vv[e] >> 16);
                    As[1][am][akh + j4 * 4 + e] = (u16)(vv[e] & 0xffffu);
                }
            }
        }
        {
            const float* wsrc = W + (size_t)(k0 + bk) * (4 * DQ) + bn * 128 + bng;
            #pragma unroll
            for (int j4 = 0; j4 < 4; ++j4) {
                float4 v = ((const float4*)wsrc)[j4];
                float vv[4] = {v.x, v.y, v.z, v.w};
                #pragma unroll
                for (int e = 0; e < 4; ++e) {
                    u16 hh16 = f2bf(vv[e]);
                    int n = bng + j4 * 4 + e;
                    Bs[0][n][bk] = hh16;
                    Bs[1][n][bk] = f2bf(vv[e] - bf2f(hh16));
                }
            }
        }
        __syncthreads();

        s8v ah[4], al[4], bh[4], bl[4];
        #pragma unroll
        for (int mt = 0; mt < 4; ++mt) {
            ah[mt] = *(const s8v*)&As[0][wm * 64 + mt * 16 + frow][quad * 8];
            al[mt] = *(const s8v*)&As[1][wm * 64 + mt * 16 + frow][quad * 8];
        }
        #pragma unroll
        for (int nt = 0; nt < 4; ++nt) {
            bh[nt] = *(const s8v*)&Bs[0][wn * 64 + nt * 16 + frow][quad * 8];
            bl[nt] = *(const s8v*)&Bs[1][wn * 64 + nt * 16 + frow][quad * 8];
        }
        #pragma unroll
        for (int mt = 0; mt < 4; ++mt)
            #pragma unroll
            for (int nt = 0; nt < 4; ++nt) {
                acc[mt][nt] = __builtin_amdgcn_mfma_f32_16x16x32_bf16(ah[mt], bh[nt], acc[mt][nt], 0, 0, 0);
                acc[mt][nt] = __builtin_amdgcn_mfma_f32_16x16x32_bf16(al[mt], bh[nt], acc[mt][nt], 0, 0, 0);
                acc[mt][nt] = __builtin_amdgcn_mfma_f32_16x16x32_bf16(ah[mt], bl[nt], acc[mt][nt], 0, 0, 0);
            }
        __syncthreads();
    }

    float bv[4];
    #pragma unroll
    for (int nt = 0; nt < 4; ++nt) bv[nt] = bias[bn * 128 + wn * 64 + nt * 16 + frow];
    #pragma unroll
    for (int mt = 0; mt < 4; ++mt) {
        #pragma unroll
        for (int nt = 0; nt < 4; ++nt) {
            int col = bn * 128 + wn * 64 + nt * 16 + frow;
            #pragma unroll
            for (int r = 0; r < 4; ++r) {
                int row = bm * 128 + wm * 64 + mt * 16 + quad * 4 + r;
                zx[(size_t)row * (4 * DQ) + col] = acc[mt][nt][r] + bv[nt];
            }
        }
    }
}

// ---------------------------------------------------------------------------
// Recurrence: 256 blocks = 2 batch-halves (bg = blk&1, aligns with XCD
// parity under blk%8 round-robin) x 128 col-groups (8 hcols). h history:
// hh[t+1] written uncached (agent atomics), read with PLAIN CACHED uint4
// loads -- fresh address per step => no staleness; per-XCD L2 dedups the
// broadcast (16 MB/step fabric -> ~0.5 MB/step). Per-half 2-level barrier.
// ---------------------------------------------------------------------------
__global__ __launch_bounds__(NTHR, 1) void lstm_rec_kernel(
    const float* __restrict__ zx,   // [B*CHUNK][4096], bias folded in
    const float* __restrict__ W,    // [2048][4096], rows [1024,2048) used
    const int* __restrict__ lens,
    u32* __restrict__ hh,           // [T+1][BQ][DQ] packed hi|lo
    u32* __restrict__ subc,         // [T][2][8] stride 16
    u32* __restrict__ topc,         // [T][2] stride 16
    float* __restrict__ state_h,    // [B*DQ]
    float* __restrict__ state_c,    // [B*DQ]
    float* __restrict__ out_f32,    // layer1: d_out (else null)
    float* __restrict__ hc_out,     // layer1: d_out + B*T*DQ (h1 then c1)
    int t0, int is_last)
{
    __shared__ u16 wt[2][32][1032];
    __shared__ float red[4][16][36];

    const int tid = threadIdx.x;
    const int blk = blockIdx.x;
    const int bg = blk & 1;          // batch-half (rows bg*16 .. +16)
    const int cg = blk >> 1;         // col-group 0..127 (hcols cg*8 .. +8)
    const int grp = (blk >> 1) & 7;  // sub-barrier group within half

    for (int idx = tid; idx < 32 * 1024; idx += NTHR) {
        int n = idx & 31, k = idx >> 5;
        int c = n >> 2, g = n & 3;
        float w = W[(size_t)(DQ + k) * (4 * DQ) + g * DQ + cg * 8 + c];
        u16 wh = f2bf(w);
        wt[0][n][k] = wh;
        wt[1][n][k] = f2bf(w - bf2f(wh));
    }

    const int gb_l = tid >> 3;       // local batch 0..15
    const int gc = tid & 7;          // local hcol 0..7
    const int b_g = bg * 16 + gb_l;
    const int hcol = cg * 8 + gc;
    float c_state = 0.f, h_state = 0.f;
    int mylen = 0;
    if (tid < 128) {
        mylen = lens[b_g];
        h_state = state_h[(size_t)b_g * DQ + hcol];
        c_state = state_c[(size_t)b_g * DQ + hcol];
    }

    const int wave = tid >> 6;
    const int lane = tid & 63;
    const int frow = lane & 15;
    const int quad = lane >> 4;
    const int ksrc = wave * 256;     // K-split across 4 waves

    __syncthreads();

    const int tend = t0 + CHUNK;
    for (int t = t0; t < tend; ++t) {
        // ---- cached h-read: slot t holds h_{t-1}; fresh address => fresh data
        const u32* hp = hh + ((size_t)t * BQ + (bg * 16 + frow)) * DQ + ksrc + quad * 8;
        uint4 q[16];
        #pragma unroll
        for (int s = 0; s < 8; ++s) {
            q[2 * s]     = ((const uint4*)(hp + s * 32))[0];
            q[2 * s + 1] = ((const uint4*)(hp + s * 32))[1];
        }

        f4v acc0 = {0.f, 0.f, 0.f, 0.f};
        f4v acc1 = {0.f, 0.f, 0.f, 0.f};
        #pragma unroll
        for (int s = 0; s < 8; ++s) {
            s8v a_h, a_l;
            unpack_pk(q[2 * s], q[2 * s + 1], a_h, a_l);
            const int koff = ksrc + s * 32 + quad * 8;
            s8v b0h = *(const s8v*)&wt[0][frow][koff];
            s8v b0l = *(const s8v*)&wt[1][frow][koff];
            s8v b1h = *(const s8v*)&wt[0][16 + frow][koff];
            s8v b1l = *(const s8v*)&wt[1][16 + frow][koff];
            acc0 = __builtin_amdgcn_mfma_f32_16x16x32_bf16(a_h, b0h, acc0, 0, 0, 0);
            acc1 = __builtin_amdgcn_mfma_f32_16x16x32_bf16(a_h, b1h, acc1, 0, 0, 0);
            acc0 = __builtin_amdgcn_mfma_f32_16x16x32_bf16(a_l, b0h, acc0, 0, 0, 0);
            acc1 = __builtin_amdgcn_mfma_f32_16x16x32_bf16(a_l, b1h, acc1, 0, 0, 0);
            acc0 = __builtin_amdgcn_mfma_f32_16x16x32_bf16(a_h, b0l, acc0, 0, 0, 0);
            acc1 = __builtin_amdgcn_mfma_f32_16x16x32_bf16(a_h, b1l, acc1, 0, 0, 0);
        }
        #pragma unroll
        for (int r = 0; r < 4; ++r) {
            red[wave][quad * 4 + r][frow] = acc0[r];
            red[wave][quad * 4 + r][16 + frow] = acc1[r];
        }

        float zxv[4];
        if (tid < 128) {
            size_t base = ((size_t)b_g * CHUNK + (t - t0)) * (4 * DQ) + hcol;
            #pragma unroll
            for (int g = 0; g < 4; ++g) zxv[g] = zx[base + (size_t)g * DQ];
        }
        __syncthreads();

        if (tid < 128) {
            float z[4];
            #pragma unroll
            for (int g = 0; g < 4; ++g) {
                int n = gc * 4 + g;
                z[g] = red[0][gb_l][n] + red[1][gb_l][n] + red[2][gb_l][n] + red[3][gb_l][n]
                     + zxv[g];
            }
            float si = 1.f / (1.f + __expf(-z[0]));
            float sf = 1.f / (1.f + __expf(-(z[2] + 1.0f)));  // forget_bias
            float so = 1.f / (1.f + __expf(-z[3]));
            float cn = sf * c_state + si * tanhf(z[1]);
            float hn = so * tanhf(cn);
            bool m = (t < mylen);
            float hk = m ? hn : h_state;
            float ck = m ? cn : c_state;
            h_state = hk; c_state = ck;

            u16 hh16 = f2bf(hk);
            u16 hl16 = f2bf(hk - bf2f(hh16));
            u32 packed = ((u32)hh16 << 16) | (u32)hl16;
            __hip_atomic_store(hh + ((size_t)(t + 1) * BQ + b_g) * DQ + hcol,
                               packed, __ATOMIC_RELAXED, __HIP_MEMORY_SCOPE_AGENT);

            if (is_last) {
                float ho = m ? hn : 0.f;
                out_f32[((size_t)b_g * TQ + t) * DQ + hcol] = ho;
            }
        }

        // ---- drain h store, then per-half 2-level barrier ----
        asm volatile("s_waitcnt vmcnt(0)" ::: "memory");
        __syncthreads();
        if (t < tend - 1) {
            if (tid == 0) {
                u32* sc = &subc[((t * 2 + bg) * 8 + grp) * 16];
                u32* tc = &topc[(t * 2 + bg) * 16];
                u32 old = atomicAdd(sc, 1u);
                if (old == 15) atomicAdd(tc, 1u);
                while (__hip_atomic_load(tc, __ATOMIC_RELAXED,
                                         __HIP_MEMORY_SCOPE_AGENT) < 8) { }
            }
            __syncthreads();
        }
    }

    if (tid < 128) {
        state_h[(size_t)b_g * DQ + hcol] = h_state;
        state_c[(size_t)b_g * DQ + hcol] = c_state;
        if (is_last && tend == TQ) {
            hc_out[(size_t)b_g * DQ + hcol] = h_state;
            hc_out[(size_t)BQ * DQ + (size_t)b_g * DQ + hcol] = c_state;
        }
    }
}

extern "C" void kernel_launch(void* const* d_in, const int* in_sizes, int n_in,
                              void* d_out, int out_size, void* d_ws, size_t ws_size,
                              hipStream_t stream) {
    const float* x    = (const float*)d_in[0];
    const int*   lens = (const int*)d_in[1];
    const float* W0   = (const float*)d_in[2];
    const float* b0   = (const float*)d_in[3];
    const float* W1   = (const float*)d_in[4];
    const float* b1   = (const float*)d_in[5];
    float* out = (float*)d_out;

    const size_t N   = (size_t)BQ * TQ * DQ;           // 16,777,216
    const size_t ZXN = (size_t)BQ * CHUNK * 4 * DQ;    // 16,777,216 f32
    const size_t HD  = (size_t)BQ * DQ;                // 32768

    float* zx  = (float*)d_ws;
    u32* hh    = (u32*)(zx + ZXN);                     // [T+1][BQ][DQ]
    // zero span: states + counters (contiguous)
    float* sh0 = (float*)(hh + (size_t)(TQ + 1) * HD);
    float* sc0 = sh0 + HD;
    float* sh1 = sc0 + HD;
    float* sc1 = sh1 + HD;
    u32* sub0  = (u32*)(sc1 + HD);
    u32* top0  = sub0 + (size_t)TQ * 2 * 8 * 16;
    u32* sub1  = top0 + (size_t)TQ * 2 * 16;
    u32* top1  = sub1 + (size_t)TQ * 2 * 8 * 16;
    u32* zend  = top1 + (size_t)TQ * 2 * 16;
    const size_t nzero = (size_t)(zend - (u32*)sh0);

    // zero hh slot 0 (h_{-1} = 0) and the state/counter span
    init_kernel<<<256, 256, 0, stream>>>(hh, HD, (u32*)sh0, nzero);

    for (int c = 0; c < NCHUNK; ++c) {
        int t0 = c * CHUNK;
        xproj_gemm_kernel<<<1024, NTHR, 0, stream>>>(x, nullptr, lens, W0, b0, zx, t0);
        lstm_rec_kernel<<<NBLK_R, NTHR, 0, stream>>>(
            zx, W0, lens, hh, sub0, top0, sh0, sc0,
            nullptr, nullptr, t0, 0);
    }
    for (int c = 0; c < NCHUNK; ++c) {
        int t0 = c * CHUNK;
        xproj_gemm_kernel<<<1024, NTHR, 0, stream>>>(nullptr, hh, lens, W1, b1, zx, t0);
        lstm_rec_kernel<<<NBLK_R, NTHR, 0, stream>>>(
            zx, W1, lens, hh, sub1, top1, sh1, sc1,
            out, out + N, t0, 1);
    }
}